// Round 5
// baseline (102.509 us; speedup 1.0000x reference)
//
#include <hip/hip_runtime.h>
#include <hip/hip_bf16.h>

typedef __bf16 bf16;
typedef __bf16 bf16x4 __attribute__((ext_vector_type(4)));
typedef __bf16 bf16x8 __attribute__((ext_vector_type(8)));
typedef float f32x4 __attribute__((ext_vector_type(4)));

#define GLOBAL_AS __attribute__((address_space(1)))
#define LDS_AS __attribute__((address_space(3)))

__device__ __forceinline__ void gload_lds16(const void* g, void* l) {
  __builtin_amdgcn_global_load_lds((const GLOBAL_AS void*)g, (LDS_AS void*)l, 16, 0, 0);
}

#define WAITV(n) asm volatile("s_waitcnt vmcnt(" #n ")" ::: "memory")

// ---- prep A: token f32 (16,256,512) -> bf16 flat (4096 x 512) ----
__global__ __launch_bounds__(256) void cvt_token_k(const float* __restrict__ t,
                                                   bf16* __restrict__ o) {
  int base = (blockIdx.x * 256 + threadIdx.x) * 4;
  f32x4 v = *(const f32x4*)(t + base);
  bf16x4 b;
  b[0] = (bf16)v[0]; b[1] = (bf16)v[1]; b[2] = (bf16)v[2]; b[3] = (bf16)v[3];
  *(bf16x4*)(o + base) = b;
}

// ---- prep B: W (512 x 16384) f32 -> Wt (16384 x 512) bf16 (B^T layout) ----
__global__ __launch_bounds__(256) void transpose_w_k(const float* __restrict__ w,
                                                     bf16* __restrict__ wt) {
  __shared__ float tile[32][33];
  int j0 = blockIdx.x * 32;
  int k0 = blockIdx.y * 32;
  int tx = threadIdx.x & 31;
  int ty = threadIdx.x >> 5;
#pragma unroll
  for (int i = 0; i < 4; ++i)
    tile[ty + i * 8][tx] = w[(size_t)(k0 + ty + i * 8) * 16384 + j0 + tx];
  __syncthreads();
#pragma unroll
  for (int i = 0; i < 4; ++i)
    wt[(size_t)(j0 + ty + i * 8) * 512 + k0 + tx] = (bf16)tile[tx][ty + i * 8];
}

// ---- fused main: GEMM1 256x256xK512, 4-phase/K-step, m201 2-barrier phases ----
// grid (hg=64, b=16), 512 threads = 8 waves = 2M x 4N; per-wave 128x64 output.
// LDS (128 KB): A[d][kk]: (d*2+kk)*16384, B[d][kk]: 65536 + (d*2+kk)*16384.
// Staging liveness + vmcnt accounting identical to (verified) round 4.
// NEW: each phase = {ds_read issue; stage; [waitv]; BAR; lgkmcnt(0);
// sched_barrier; setprio+16 MFMA+setprio; BAR} — all-wave LDS-read window
// overlaps prior phase's MFMA pipe drain (m201's lever).
__global__ __launch_bounds__(512, 2) void fused_main_k(
    const bf16* __restrict__ A, const bf16* __restrict__ Wt,
    const float* __restrict__ bias, float* __restrict__ out) {
  __shared__ char smem[131072];
  const int tid = threadIdx.x;
  const int lane = tid & 63;
  const int w = tid >> 6;
  const int wm = w >> 2;   // 0..1 (128-row group)
  const int wn = w & 3;    // 0..3 (64-col group)
  const int b = blockIdx.y;
  const int hg = blockIdx.x;
  const int m0 = b << 8;
  const int j0 = hg << 8;

  int rS[2], kS[2];
#pragma unroll
  for (int i = 0; i < 2; ++i) {
    int c = i * 512 + tid;
    rS[i] = c >> 2;
    kS[i] = ((c & 3) ^ ((rS[i] >> 1) & 3)) << 3;
  }
  const bf16* Abase = A + (size_t)m0 * 512;
  const bf16* Bbase = Wt + (size_t)j0 * 512;

  int offA[2][4], offB[4];
#pragma unroll
  for (int mh = 0; mh < 2; ++mh)
#pragma unroll
    for (int q = 0; q < 4; ++q) {
      int r = wm * 128 + mh * 64 + q * 16 + (lane & 15);
      offA[mh][q] = r * 64 + (((lane >> 4) ^ ((r >> 1) & 3)) << 4);
    }
#pragma unroll
  for (int nf = 0; nf < 4; ++nf) {
    int r = wn * 64 + nf * 16 + (lane & 15);
    offB[nf] = r * 64 + (((lane >> 4) ^ ((r >> 1) & 3)) << 4);
  }

#define STAGE_A(t_, kk_, d_) do { \
    gload_lds16(Abase + (size_t)rS[0]*512 + ((t_)<<6) + ((kk_)<<5) + kS[0], \
                smem + ((d_)*2 + (kk_))*16384 + (w*64)*16); \
    gload_lds16(Abase + (size_t)rS[1]*512 + ((t_)<<6) + ((kk_)<<5) + kS[1], \
                smem + ((d_)*2 + (kk_))*16384 + (512 + w*64)*16); \
  } while (0)
#define STAGE_B(t_, kk_, d_) do { \
    gload_lds16(Bbase + (size_t)rS[0]*512 + ((t_)<<6) + ((kk_)<<5) + kS[0], \
                smem + 65536 + ((d_)*2 + (kk_))*16384 + (w*64)*16); \
    gload_lds16(Bbase + (size_t)rS[1]*512 + ((t_)<<6) + ((kk_)<<5) + kS[1], \
                smem + 65536 + ((d_)*2 + (kk_))*16384 + (512 + w*64)*16); \
  } while (0)

  // m201 2-barrier phase tail: pre-MFMA barrier, lgkm drain, pinned MFMA, post-barrier
#define PRE_MFMA() do { \
    asm volatile("" ::: "memory"); \
    __builtin_amdgcn_s_barrier(); \
    asm volatile("s_waitcnt lgkmcnt(0)" ::: "memory"); \
    __builtin_amdgcn_sched_barrier(0); \
    __builtin_amdgcn_s_setprio(1); \
  } while (0)
#define POST_MFMA() do { \
    __builtin_amdgcn_s_setprio(0); \
    asm volatile("" ::: "memory"); \
    __builtin_amdgcn_s_barrier(); \
    asm volatile("" ::: "memory"); \
  } while (0)

  f32x4 acc[8][4] = {};

  // ---- prologue: 6 halves (12 loads); oldest 4 = step0's k0 halves ----
  STAGE_A(0, 0, 0); STAGE_B(0, 0, 0);
  STAGE_A(0, 1, 0); STAGE_B(0, 1, 0);
  STAGE_A(1, 0, 1); STAGE_B(1, 0, 1);
  WAITV(8);  // A-k0(0), B-k0(0) landed; 8 in flight
  asm volatile("" ::: "memory");
  __builtin_amdgcn_s_barrier();
  asm volatile("" ::: "memory");

  // ---- K-loop: 8 steps of BK=64, 4 phases each ----
#pragma unroll
  for (int t = 0; t < 8; ++t) {
    const int d = t & 1;
    const char* Ak0 = smem + (d * 2 + 0) * 16384;
    const char* Ak1 = smem + (d * 2 + 1) * 16384;
    const char* Bk0 = smem + 65536 + (d * 2 + 0) * 16384;
    const char* Bk1 = smem + 65536 + (d * 2 + 1) * 16384;
    bf16x8 af[4], bfr[4];

    // ---- p1: (mh0, k0); stage A-k1(t+1) -> d^1 ----
#pragma unroll
    for (int nf = 0; nf < 4; ++nf) bfr[nf] = *(const bf16x8*)(Bk0 + offB[nf]);
#pragma unroll
    for (int q = 0; q < 4; ++q) af[q] = *(const bf16x8*)(Ak0 + offA[0][q]);
    if (t + 1 < 8) STAGE_A(t + 1, 1, d ^ 1);
    PRE_MFMA();
#pragma unroll
    for (int q = 0; q < 4; ++q)
#pragma unroll
      for (int nf = 0; nf < 4; ++nf)
        acc[q][nf] = __builtin_amdgcn_mfma_f32_16x16x32_bf16(af[q], bfr[nf], acc[q][nf], 0, 0, 0);
    POST_MFMA();

    // ---- p2: (mh1, k0); stage B-k1(t+1) -> d^1 ----
#pragma unroll
    for (int q = 0; q < 4; ++q) af[q] = *(const bf16x8*)(Ak0 + offA[1][q]);
    if (t + 1 < 8) STAGE_B(t + 1, 1, d ^ 1);
    PRE_MFMA();
#pragma unroll
    for (int q = 0; q < 4; ++q)
#pragma unroll
      for (int nf = 0; nf < 4; ++nf)
        acc[4 + q][nf] = __builtin_amdgcn_mfma_f32_16x16x32_bf16(af[q], bfr[nf], acc[4 + q][nf], 0, 0, 0);
    __builtin_amdgcn_s_setprio(0);
    asm volatile("" ::: "memory");
    if (t == 7) { WAITV(0); } else { WAITV(8); }  // retire A/B-k1(t) halves
    __builtin_amdgcn_s_barrier();
    asm volatile("" ::: "memory");

    // ---- p3: (mh0, k1); stage A-k0(t+2) -> d (k0(d) dead after p2) ----
#pragma unroll
    for (int nf = 0; nf < 4; ++nf) bfr[nf] = *(const bf16x8*)(Bk1 + offB[nf]);
#pragma unroll
    for (int q = 0; q < 4; ++q) af[q] = *(const bf16x8*)(Ak1 + offA[0][q]);
    if (t + 2 < 8) STAGE_A(t + 2, 0, d);
    PRE_MFMA();
#pragma unroll
    for (int q = 0; q < 4; ++q)
#pragma unroll
      for (int nf = 0; nf < 4; ++nf)
        acc[q][nf] = __builtin_amdgcn_mfma_f32_16x16x32_bf16(af[q], bfr[nf], acc[q][nf], 0, 0, 0);
    POST_MFMA();

    // ---- p4: (mh1, k1); stage B-k0(t+2) -> d ----
#pragma unroll
    for (int q = 0; q < 4; ++q) af[q] = *(const bf16x8*)(Ak1 + offA[1][q]);
    if (t + 2 < 8) STAGE_B(t + 2, 0, d);
    PRE_MFMA();
#pragma unroll
    for (int q = 0; q < 4; ++q)
#pragma unroll
      for (int nf = 0; nf < 4; ++nf)
        acc[4 + q][nf] = __builtin_amdgcn_mfma_f32_16x16x32_bf16(af[q], bfr[nf], acc[4 + q][nf], 0, 0, 0);
    __builtin_amdgcn_s_setprio(0);
    asm volatile("" ::: "memory");
    if (t < 6) { WAITV(8); } else if (t == 6) { WAITV(4); }  // retire A/B-k0(t+1)
    __builtin_amdgcn_s_barrier();
    asm volatile("" ::: "memory");
  }
#undef STAGE_A
#undef STAGE_B
#undef PRE_MFMA
#undef POST_MFMA

  // ---- epilogue: bias + silu + rope on k; write k/v bf16 to LDS [ch][d][n] ----
#pragma unroll
  for (int nf = 0; nf < 4; ++nf) {
    const int col = wn * 64 + nf * 16 + (lane & 15);  // 0..255
    const int chl = col >> 5;                         // 0..7 local channel
    const int dd = lane & 15;
    const bool isk = ((nf & 1) == 0);
    const float bv = bias[j0 + col];
    float freq = 0.f, sgn = 0.f;
    if (isk) {
      const int tp = dd >> 1;
      const int chg = (hg << 3) + chl;
      freq = exp2f((float)(chg * 8 + tp) * (-13.287712379549449f / 4096.0f));
      sgn = (dd & 1) ? 1.0f : -1.0f;
    }
#pragma unroll
    for (int mf = 0; mf < 8; ++mf) {
      const int n0 = wm * 128 + mf * 16 + ((lane >> 4) << 2);
      f32x4 c = acc[mf][nf];
#pragma unroll
      for (int j = 0; j < 4; ++j) {
        float x = c[j] + bv;
        if (isk) x = x * __builtin_amdgcn_rcpf(1.0f + __expf(-x));  // silu
        c[j] = x;
      }
      if (isk) {
#pragma unroll
        for (int j = 0; j < 4; ++j) {
          float partner = __shfl_xor(c[j], 1);  // pre-update value, lockstep
          float sv, cv;
          __sincosf(freq * (float)(255 - (n0 + j)), &sv, &cv);
          c[j] = c[j] * cv + sgn * partner * sv;
        }
      }
      bf16x4 pk;
      pk[0] = (bf16)c[0]; pk[1] = (bf16)c[1]; pk[2] = (bf16)c[2]; pk[3] = (bf16)c[3];
      int byte = (isk ? 0 : 65536) + chl * 8192 + dd * 512 + n0 * 2;
      byte ^= ((dd & 7) << 4);  // bank swizzle
      *(bf16x4*)(smem + byte) = pk;
    }
  }
  __syncthreads();

  // ---- GEMM2: wave w owns channel w fully (all 256 n): 8 MFMAs ----
  {
    const int dd = lane & 15;
    f32x4 d2 = {0.f, 0.f, 0.f, 0.f};
#pragma unroll
    for (int kk2 = 0; kk2 < 8; ++kk2) {
      const int n0 = kk2 * 32 + ((lane >> 4) << 3);
      int byte = w * 8192 + dd * 512 + n0 * 2;
      byte ^= ((dd & 7) << 4);
      bf16x8 ka = *(const bf16x8*)(smem + byte);           // k^T: [d][n]
      bf16x8 vb = *(const bf16x8*)(smem + 65536 + byte);   // v:   [e][n]
      d2 = __builtin_amdgcn_mfma_f32_16x16x32_bf16(ka, vb, d2, 0, 0, 0);
    }
    __syncthreads();  // all k/v reads done before partials overwrite
    float* part = (float*)smem;  // [256 de][8 ch]
#pragma unroll
    for (int j = 0; j < 4; ++j) {
      int de = (((lane >> 4) << 2) + j) * 16 + dd;  // d*16+e
      part[de * 8 + w] = d2[j];
    }
  }
  __syncthreads();

  // ---- output: thread t -> de=t>>1, 4 consecutive channels ----
  {
    const float* part = (const float*)smem;
    int de = tid >> 1, c4 = (tid & 1) << 2;
    f32x4 o = *(const f32x4*)(part + de * 8 + c4);
    *(f32x4*)(out + (size_t)b * 131072 + (size_t)de * 512 + (hg << 3) + c4) = o;
  }
}

extern "C" void kernel_launch(void* const* d_in, const int* in_sizes, int n_in,
                              void* d_out, int out_size, void* d_ws, size_t ws_size,
                              hipStream_t stream) {
  const float* token = (const float*)d_in[0];   // (16,256,512) f32
  const float* W     = (const float*)d_in[1];   // (512,16384) f32
  const float* bias  = (const float*)d_in[2];   // (16384,) f32
  float* out = (float*)d_out;                   // (16,256,512) f32

  bf16* Abf = (bf16*)d_ws;                                    // 4 MB
  bf16* Wt  = (bf16*)((char*)d_ws + (size_t)4 * 1024 * 1024); // 16 MB

  cvt_token_k<<<2048, 256, 0, stream>>>(token, Abf);
  transpose_w_k<<<dim3(512, 16), 256, 0, stream>>>(W, Wt);
  fused_main_k<<<dim3(64, 16), 512, 0, stream>>>(Abf, Wt, bias, out);
}

// Round 7
// 96.349 us; speedup vs baseline: 1.0639x; 1.0639x over previous
//
#include <hip/hip_runtime.h>
#include <hip/hip_bf16.h>

typedef __bf16 bf16;
typedef __bf16 bf16x4 __attribute__((ext_vector_type(4)));
typedef __bf16 bf16x8 __attribute__((ext_vector_type(8)));
typedef float f32x4 __attribute__((ext_vector_type(4)));

#define GLOBAL_AS __attribute__((address_space(1)))
#define LDS_AS __attribute__((address_space(3)))

__device__ __forceinline__ void gload_lds16(const void* g, void* l) {
  __builtin_amdgcn_global_load_lds((const GLOBAL_AS void*)g, (LDS_AS void*)l, 16, 0, 0);
}
#define WAITV(n) asm volatile("s_waitcnt vmcnt(" #n ")" ::: "memory")

// ---- prep A: token f32 (4096x512) -> fragment-major A_pack bf16 (4 MB) ----
// group g = b*256 + kb*16 + wr*4 + mf; elem = g*512 + lane*8 + e
// content: token[b*256 + wr*64 + mf*16 + (lane&15)][kb*32 + (lane>>4)*8 + e]
__global__ __launch_bounds__(256) void pack_a_k(const float* __restrict__ t,
                                                bf16* __restrict__ o) {
  int g = blockIdx.x * 4 + (threadIdx.x >> 6);
  int lane = threadIdx.x & 63;
  int mf = g & 3, wr = (g >> 2) & 3, kb = (g >> 4) & 15, b = g >> 8;
  int m = (b << 8) + (wr << 6) + (mf << 4) + (lane & 15);
  int k = (kb << 5) + ((lane >> 4) << 3);
  const float* src = t + (size_t)m * 512 + k;
  f32x4 v0 = *(const f32x4*)src;
  f32x4 v1 = *(const f32x4*)(src + 4);
  bf16x8 p;
  p[0] = (bf16)v0[0]; p[1] = (bf16)v0[1]; p[2] = (bf16)v0[2]; p[3] = (bf16)v0[3];
  p[4] = (bf16)v1[0]; p[5] = (bf16)v1[1]; p[6] = (bf16)v1[2]; p[7] = (bf16)v1[3];
  *(bf16x8*)(o + ((size_t)g << 9) + (lane << 3)) = p;
}

// ---- prep B: W f32 (512x16384) -> fragment-major B_pack bf16 (16 MB) ----
// frag (jg = hg*2+wc, kb, nf): elem = (((jg*16+kb)*4+nf)*512) + lane*8 + e
// content: W[kb*32 + (lane>>4)*8 + e][jg*64 + nf*16 + (lane&15)]
__global__ __launch_bounds__(256) void pack_b_k(const float* __restrict__ wsrc,
                                                bf16* __restrict__ o) {
  __shared__ float tile[32][65];
  int tileid = blockIdx.x;            // 4096 tiles = jg(256) x kb(16)
  int kb = tileid & 15, jg = tileid >> 4;
  int k0 = kb << 5, j0 = jg << 6;
  int tid = threadIdx.x;
  // load 32k x 64j f32: thread r=tid>>3 (0..31), c8=(tid&7)*8
  {
    int r = tid >> 3, c8 = (tid & 7) << 3;
    const float* src = wsrc + (size_t)(k0 + r) * 16384 + j0 + c8;
    f32x4 a = *(const f32x4*)src;
    f32x4 b2 = *(const f32x4*)(src + 4);
    *(f32x4*)&tile[r][c8] = a;
    *(f32x4*)&tile[r][c8 + 4] = b2;
  }
  __syncthreads();
  // write: lr = tid&15 (col), khi = (tid>>4)&3 (k-high), nf = tid>>6
  // FIX (R6 bug): in-fragment offset is (tid&63)*8, NOT tid*8 — frag base
  // already contains nf*512; tid*8 double-counted nf and corrupted B_pack.
  int lr = tid & 15, khi = (tid >> 4) & 3, nf = tid >> 6;
  int j = (nf << 4) + lr, kk = khi << 3;
  bf16x8 p;
#pragma unroll
  for (int e = 0; e < 8; ++e) p[e] = (bf16)tile[kk + e][j];
  *(bf16x8*)(o + ((size_t)(((jg << 4) + kb) * 4 + nf) << 9) + ((tid & 63) << 3)) = p;
}

// ---- fused main: GEMM1 256x128xK512 (A via LDS triple-buf, B global->reg)
//      + bias + silu + rope + GEMM2 ----
// grid (hg=128, b=16), 512 threads = 8 waves (wr=w>>1 row-group, wc=w&1 col-group)
// LDS 64 KB: GEMM phase A bufs 3x16KB (fragment-linear, conflict-free);
//            epilogue k[0..32K) v[32K..64K) (R1-verbatim).
// K-loop (16 x BK=32): issue bfr(t+1) reg-loads + stage A(t+2) -> buf[(t+2)%3];
// ds_read af(t) (sequential, 0-conflict); 16 MFMA; WAITV(2) retires
// bfr(t+1)+A(t+1), keeps A(t+2) in flight (T4); 1 barrier/step (R3-proven).
__global__ __launch_bounds__(512, 4) void fused_main_k(
    const bf16* __restrict__ Ap, const bf16* __restrict__ Bp,
    const float* __restrict__ bias, float* __restrict__ out) {
  __shared__ char smem[65536];
  const int tid = threadIdx.x;
  const int lane = tid & 63;
  const int w = tid >> 6;
  const int wr = w >> 1;   // 0..3 (64-row group)
  const int wc = w & 1;    // 0..1 (64-col group)
  const int b = blockIdx.y;
  const int hg = blockIdx.x;
  const int j0 = hg << 7;

  const bf16* Abase = Ap + ((size_t)(b * 16) << 13);                 // +kb*8192 elems
  const bf16* Bbase = Bp + ((size_t)((hg * 2 + wc) * 16) << 11);     // +kb*2048 elems

  f32x4 acc[4][4] = {};
  bf16x8 bfA[4], bfB[4];  // bfr double buffer (even/odd t)

#define LOAD_BFR(dst_, kb_) do { \
    const bf16* p_ = Bbase + ((kb_) * 2048) + (lane << 3); \
    dst_[0] = *(const bf16x8*)(p_);        \
    dst_[1] = *(const bf16x8*)(p_ + 512);  \
    dst_[2] = *(const bf16x8*)(p_ + 1024); \
    dst_[3] = *(const bf16x8*)(p_ + 1536); \
  } while (0)
#define STAGE_A(kb_, buf_) do { \
    gload_lds16(Abase + ((size_t)(kb_) << 13) + (tid << 3), \
                smem + (buf_) * 16384 + tid * 16); \
    gload_lds16(Abase + ((size_t)(kb_) << 13) + ((tid + 512) << 3), \
                smem + (buf_) * 16384 + (tid + 512) * 16); \
  } while (0)

  // prologue: bfr(0) first (oldest in vmcnt queue), then A(0), A(1)
  LOAD_BFR(bfA, 0);
  STAGE_A(0, 0);
  STAGE_A(1, 1);
  WAITV(2);  // bfr0 + A0 landed; A1's 2 loads in flight
  __builtin_amdgcn_s_barrier();
  asm volatile("" ::: "memory");

  // ---- K-loop: 16 steps of BK=32 ----
#pragma unroll
  for (int t = 0; t < 16; ++t) {
    const int cb = (t % 3) * 16384;
    if (t < 15) { if (t & 1) LOAD_BFR(bfA, t + 1); else LOAD_BFR(bfB, t + 1); }
    if (t < 14) STAGE_A(t + 2, (t + 2) % 3);
    bf16x8 af[4];
#pragma unroll
    for (int mf = 0; mf < 4; ++mf)
      af[mf] = *(const bf16x8*)(smem + cb + ((wr * 4 + mf) << 10) + (lane << 4));
    __builtin_amdgcn_s_setprio(1);
#pragma unroll
    for (int mf = 0; mf < 4; ++mf)
#pragma unroll
      for (int nf = 0; nf < 4; ++nf)
        acc[mf][nf] = __builtin_amdgcn_mfma_f32_16x16x32_bf16(
            af[mf], (t & 1) ? bfB[nf] : bfA[nf], acc[mf][nf], 0, 0, 0);
    __builtin_amdgcn_s_setprio(0);
    asm volatile("" ::: "memory");
    if (t < 14) { WAITV(2); } else { WAITV(0); }
    __builtin_amdgcn_s_barrier();
    asm volatile("" ::: "memory");
  }
#undef LOAD_BFR
#undef STAGE_A

  // ---- epilogue: bias + silu + rope on k-half; write k/v bf16 to LDS [h][d][n] ----
#pragma unroll
  for (int nf = 0; nf < 4; ++nf) {
    const int col = wc * 64 + nf * 16 + (lane & 15);  // 0..127
    const int hl = col >> 5;                          // 0..3 local head
    const int dd = lane & 15;                         // d within 16
    const bool isk = ((nf & 1) == 0);                 // cols d<16 are k
    const float bv = bias[j0 + col];
    float freq = 0.f, sgn = 0.f;
    if (isk) {
      const int tp = dd >> 1;
      const int hglob = (hg << 2) + hl;
      freq = exp2f((float)(hglob * 8 + tp) * (-13.287712379549449f / 4096.0f));
      sgn = (dd & 1) ? 1.0f : -1.0f;
    }
#pragma unroll
    for (int mf = 0; mf < 4; ++mf) {
      const int n0 = wr * 64 + mf * 16 + ((lane >> 4) << 2);
      f32x4 c = acc[mf][nf];
#pragma unroll
      for (int j = 0; j < 4; ++j) {
        float x = c[j] + bv;
        if (isk) x = x * __builtin_amdgcn_rcpf(1.0f + __expf(-x));  // silu
        c[j] = x;
      }
      if (isk) {
#pragma unroll
        for (int j = 0; j < 4; ++j) {
          float partner = __shfl_xor(c[j], 1);  // pre-update value, lockstep
          float sv, cv;
          __sincosf(freq * (float)(255 - (n0 + j)), &sv, &cv);
          c[j] = c[j] * cv + sgn * partner * sv;
        }
      }
      bf16x4 pk;
      pk[0] = (bf16)c[0]; pk[1] = (bf16)c[1]; pk[2] = (bf16)c[2]; pk[3] = (bf16)c[3];
      int byte = (isk ? 0 : 32768) + hl * 8192 + dd * 512 + n0 * 2;
      byte ^= ((dd & 7) << 4);  // bank swizzle
      *(bf16x4*)(smem + byte) = pk;
    }
  }
  __syncthreads();

  // ---- GEMM2: wave w -> head hl=w>>1, n-half=w&1; 4 MFMAs over 128 n ----
  {
    const int hl = w >> 1;
    const int half = w & 1;
    const int dd = lane & 15;
    f32x4 d2 = {0.f, 0.f, 0.f, 0.f};
#pragma unroll
    for (int kk = 0; kk < 4; ++kk) {
      const int n0 = half * 128 + kk * 32 + ((lane >> 4) << 3);
      int byte = hl * 8192 + dd * 512 + n0 * 2;
      byte ^= ((dd & 7) << 4);
      bf16x8 ka = *(const bf16x8*)(smem + byte);           // A = k^T: [d][n]
      bf16x8 vb = *(const bf16x8*)(smem + 32768 + byte);   // B = v:   [e][n]
      d2 = __builtin_amdgcn_mfma_f32_16x16x32_bf16(ka, vb, d2, 0, 0, 0);
    }
    __syncthreads();  // all k/v reads done before partials overwrite
    float* part = (float*)smem;  // [8][256]
#pragma unroll
    for (int j = 0; j < 4; ++j) {
      int de = (((lane >> 4) << 2) + j) * 16 + dd;  // d*16+e
      part[w * 256 + de] = d2[j];
    }
  }
  __syncthreads();

  // ---- combine wave-pair partials, coalesced float4 store ----
  if (tid < 256) {
    const float* part = (const float*)smem;
    f32x4 o;
#pragma unroll
    for (int hl = 0; hl < 4; ++hl)
      o[hl] = part[(2 * hl) * 256 + tid] + part[(2 * hl + 1) * 256 + tid];
    *(f32x4*)(out + (size_t)b * 131072 + (size_t)tid * 512 + hg * 4) = o;
  }
}

extern "C" void kernel_launch(void* const* d_in, const int* in_sizes, int n_in,
                              void* d_out, int out_size, void* d_ws, size_t ws_size,
                              hipStream_t stream) {
  const float* token = (const float*)d_in[0];   // (16,256,512) f32
  const float* W     = (const float*)d_in[1];   // (512,16384) f32
  const float* bias  = (const float*)d_in[2];   // (16384,) f32
  float* out = (float*)d_out;                   // (16,256,512) f32

  bf16* Apack = (bf16*)d_ws;                                    // 4 MB
  bf16* Bpack = (bf16*)((char*)d_ws + (size_t)4 * 1024 * 1024); // 16 MB

  pack_a_k<<<1024, 256, 0, stream>>>(token, Apack);
  pack_b_k<<<4096, 256, 0, stream>>>(W, Bpack);
  fused_main_k<<<dim3(128, 16), 512, 0, stream>>>(Apack, Bpack, bias, out);
}